// Round 1
// baseline (660.332 us; speedup 1.0000x reference)
//
#include <hip/hip_runtime.h>
#include <math.h>

#define DIM 128

// lower_bound over sorted int array; all arguments are blockIdx-uniform so
// the compiler emits scalar loads.
__device__ __forceinline__ int lower_bound_i(const int* __restrict__ b, int n, int key) {
    int lo = 0, hi = n;
    while (lo < hi) {
        int mid = (lo + hi) >> 1;
        if (b[mid] < key) lo = mid + 1; else hi = mid;
    }
    return lo;
}

// One block per graph. 256 threads = 4 waves = 8 half-wave node-streams.
// Each 32-lane half processes one node per iteration: lane holds float4 of the
// 128-dim row, dot-reduces via 5 xor-shuffles (masks <= 16 stay within the
// half), maintains online-softmax state (m, l, o[128]) in registers.
__global__ __launch_bounds__(256) void attnpool_kernel(
    const float* __restrict__ x, const float* __restrict__ q,
    const int* __restrict__ batch, float* __restrict__ out, int n)
{
    const int g    = blockIdx.x;
    const int tid  = threadIdx.x;
    const int wave = tid >> 6;
    const int lane = tid & 63;
    const int half = lane >> 5;   // 0 or 1
    const int hl   = lane & 31;   // lane within half

    const int lo = lower_bound_i(batch, n, g);
    const int hi = lower_bound_i(batch, n, g + 1);

    // per-lane query fragment (dims hl*4 .. hl*4+3)
    const float4 qf = *(const float4*)(q + hl * 4);

    float  m = -INFINITY;
    float  l = 0.f;
    float4 o = make_float4(0.f, 0.f, 0.f, 0.f);

    // node-stream id = wave*2 + half, 8 streams, stride 8
    for (int i = lo + wave * 2 + half; i < hi; i += 8) {
        const float4 xv = *(const float4*)(x + (size_t)i * DIM + hl * 4);
        float s = xv.x * qf.x + xv.y * qf.y + xv.z * qf.z + xv.w * qf.w;
        s += __shfl_xor(s, 16);
        s += __shfl_xor(s, 8);
        s += __shfl_xor(s, 4);
        s += __shfl_xor(s, 2);
        s += __shfl_xor(s, 1);
        float p;
        if (s > m) {               // half-wave-uniform branch, rare in steady state
            const float a = __expf(m - s);   // exp(-inf)=0 handles first node
            l *= a;
            o.x *= a; o.y *= a; o.z *= a; o.w *= a;
            m = s;
            p = 1.f;
        } else {
            p = __expf(s - m);
        }
        l += p;
        o.x += p * xv.x; o.y += p * xv.y; o.z += p * xv.z; o.w += p * xv.w;
    }

    // merge the 8 partial online-softmax states through LDS
    __shared__ float sm_m[8];
    __shared__ float sm_l[8];
    __shared__ float sm_o[8 * DIM];
    const int idx = wave * 2 + half;
    if (hl == 0) { sm_m[idx] = m; sm_l[idx] = l; }
    *(float4*)(sm_o + idx * DIM + hl * 4) = o;
    __syncthreads();

    if (tid < DIM) {
        float M = -INFINITY;
        #pragma unroll
        for (int h = 0; h < 8; ++h)
            if (sm_l[h] > 0.f && sm_m[h] > M) M = sm_m[h];
        float L = 0.f, O = 0.f;
        #pragma unroll
        for (int h = 0; h < 8; ++h) {
            if (sm_l[h] > 0.f) {
                const float c = __expf(sm_m[h] - M);
                L += c * sm_l[h];
                O += c * sm_o[h * DIM + tid];
            }
        }
        // empty segment -> L==0 -> write 0 (matches segment_sum identity)
        out[(size_t)g * DIM + tid] = (L > 0.f) ? (O / L) : 0.f;
    }
}

extern "C" void kernel_launch(void* const* d_in, const int* in_sizes, int n_in,
                              void* d_out, int out_size, void* d_ws, size_t ws_size,
                              hipStream_t stream) {
    const float* x     = (const float*)d_in[0];
    const float* q     = (const float*)d_in[1];
    const int*   batch = (const int*)d_in[2];
    float*       out   = (float*)d_out;
    const int n          = in_sizes[0] / DIM;   // 1,000,000
    const int num_graphs = out_size / DIM;      // 4096
    attnpool_kernel<<<num_graphs, 256, 0, stream>>>(x, q, batch, out, n);
}